// Round 5
// baseline (4929.877 us; speedup 1.0000x reference)
//
#include <hip/hip_runtime.h>
#include <hip/hip_bf16.h>
#include <cstdint>

#define NB 8192
#define TSTEPS 48

typedef __hip_bfloat16 bf16;
typedef short bf16x8 __attribute__((ext_vector_type(8)));
typedef float f32x4 __attribute__((ext_vector_type(4)));

__device__ __forceinline__ float sigf(float x) { return 1.0f / (1.0f + __expf(-x)); }
__device__ __forceinline__ float tanhf_fast(float x) { return 2.0f / (1.0f + __expf(-2.0f * x)) - 1.0f; }

// CK-style async global->LDS, 16B per lane. LDS dest = wave-uniform base + lane*16.
__device__ __forceinline__ void gld_lds16(const void* g, void* l) {
  typedef const __attribute__((address_space(1))) unsigned int* gp_t;
  typedef __attribute__((address_space(3))) unsigned int* lp_t;
  __builtin_amdgcn_global_load_lds(reinterpret_cast<gp_t>(reinterpret_cast<uintptr_t>(g)),
                                   reinterpret_cast<lp_t>(reinterpret_cast<uintptr_t>(l)),
                                   16, 0, 0);
}

// agent-scope polling spin (called by one thread); capped so bugs fail-wrong, not hang
__device__ __forceinline__ void spin_ge(unsigned* p, unsigned target) {
  int guard = 0;
  while (__hip_atomic_load(p, __ATOMIC_RELAXED, __HIP_MEMORY_SCOPE_AGENT) < target) {
    __builtin_amdgcn_s_sleep(2);
    if (++guard > 20000000) break;
  }
}

// ---------------- feats precompute: [T, N, 32] bf16, upper 16 cols zero ----------------
__global__ void feats_kernel(const float* __restrict__ x, const float* __restrict__ coords,
                             const float* __restrict__ env, const float* __restrict__ areas,
                             const float* __restrict__ bird, bf16* __restrict__ feats) {
  int idx = blockIdx.x * 256 + threadIdx.x;  // = t*NB + n
  int n = idx & (NB - 1);
  int t = idx >> 13;
  __align__(16) bf16 v[32];
  v[0] = __float2bfloat16(x[n * TSTEPS + t]);
  v[1] = __float2bfloat16(coords[n * 2 + 0]);
  v[2] = __float2bfloat16(coords[n * 2 + 1]);
#pragma unroll
  for (int e = 0; e < 10; ++e) v[3 + e] = __float2bfloat16(env[(n * 10 + e) * TSTEPS + t]);
  v[13] = __float2bfloat16(areas[n]);
  v[14] = __float2bfloat16(bird[(n * 2 + 0) * TSTEPS + t]);
  v[15] = __float2bfloat16(bird[(n * 2 + 1) * TSTEPS + t]);
#pragma unroll
  for (int f = 16; f < 32; ++f) v[f] = __float2bfloat16(0.0f);
  bf16* dst = feats + (size_t)idx * 32;
#pragma unroll
  for (int c = 0; c < 4; ++c) ((bf16x8*)dst)[c] = ((const bf16x8*)v)[c];
}

// ---------------- weight packing ----------------
// packed gate-column order: j' = 128*q + 32*g + s  <->  original row j = 256*g + 32*q + s
__device__ __forceinline__ int orig_row(int jp) {
  int q = jp >> 7, g = (jp >> 5) & 3, s = jp & 31;
  return g * 256 + q * 32 + s;
}

// WA: [1024, 288] = [W_hh0 (256) | Wc0 = W_ih0@W_in (16) | zeros (16)]
__global__ void packA_kernel(const float* __restrict__ W_hh0, const float* __restrict__ W_ih0,
                             const float* __restrict__ W_in, bf16* __restrict__ WA) {
  int idx = blockIdx.x * 256 + threadIdx.x;  // < 1024*288
  int jp = idx / 288, col = idx % 288;
  int j = orig_row(jp);
  float val = 0.0f;
  if (col < 256) {
    val = W_hh0[j * 256 + col];
  } else if (col < 272) {
    int f = col - 256;
    float s = 0.0f;
    for (int k = 0; k < 256; ++k) s += W_ih0[j * 256 + k] * W_in[k * 16 + f];
    val = s;
  }
  WA[(size_t)jp * 288 + col] = __float2bfloat16(val);
}

// WB: [1024, 512] = [W_ih1 (256) | W_hh1 (256)]
__global__ void packB_kernel(const float* __restrict__ W_ih1, const float* __restrict__ W_hh1,
                             bf16* __restrict__ WB) {
  int idx = blockIdx.x * 256 + threadIdx.x;  // < 1024*512
  int jp = idx >> 9, col = idx & 511;
  int j = orig_row(jp);
  float val = (col < 256) ? W_ih1[j * 256 + col] : W_hh1[j * 256 + (col - 256)];
  WB[(size_t)jp * 512 + col] = __float2bfloat16(val);
}

__global__ void packBias_kernel(const float* __restrict__ b_ih, const float* __restrict__ b_hh,
                                float* __restrict__ bA, float* __restrict__ bB) {
  int idx = blockIdx.x * 256 + threadIdx.x;  // < 2048
  int layer = idx >> 10, jp = idx & 1023;
  int j = orig_row(jp);
  float v = b_ih[layer * 1024 + j] + b_hh[layer * 1024 + j];
  if (layer == 0) bA[jp] = v; else bB[jp] = v;
}

// ---------------- persistent fused LSTM ----------------
// grid = 512 blocks (64 rowgroups x 8 q), 2 blocks/CU guaranteed by
// __launch_bounds__(256,2) + 33.8KB LDS + grid == 2*256. Block (rg,q) owns rows
// [rg*128, rg*128+128) x units [q*32, q*32+32) of BOTH layers for all 48 steps;
// c0/c1 slices live in registers (16 f32 x 2 per thread).
// Dependency epochs (8 incs per rowgroup per step):
//   pre-A(t):  cntA >= 8t          (h0(t-1) complete; h0 slot overwrite safe:
//                                   A(t-1) readers done via same, B(t-2) readers
//                                   done via previous pre-B spin cntB >= 8(t-1))
//   pre-B(t):  cntA >= 8(t+1)      (h0(t) complete)
//              cntB >= 8t          (h1(t-1) complete + h1 slot overwrite safe)
// Cross-XCD visibility: __threadfence() (agent fence -> buffer_wbl2/buffer_inv sc1)
// before each inc and after each successful spin, by tid0, ordered via s_barrier.
__global__ __launch_bounds__(256, 2) void lstm_persistent(
    bf16* __restrict__ h0, bf16* __restrict__ h1,  // each [2][8192][256]
    const bf16* __restrict__ feats,
    const bf16* __restrict__ WA, const bf16* __restrict__ WB,
    const float* __restrict__ bA, const float* __restrict__ bB,
    unsigned* __restrict__ cntA, unsigned* __restrict__ cntB,
    float* __restrict__ out) {
  __shared__ float Gs[64 * 132];
  bf16* As = (bf16*)Gs;        // [128][32]
  bf16* Bs = As + 128 * 32;    // [128][32]

  const int tid = threadIdx.x;
  const int wid = tid >> 6, lane = tid & 63;
  const int quad = lane >> 4, l16 = lane & 15;
  const int mb = (wid >> 1) * 64, nb = (wid & 1) * 64;
  const int rg = blockIdx.x >> 3;
  const int q = blockIdx.x & 7;
  const int rowbase = rg * 128;

  const int arow = wid * 32 + (lane >> 2);  // staging row within 128-tile
  const int achunk = (lane & 3) * 8;
  bf16* lA = As + wid * 1024;  // wave-uniform LDS staging bases
  bf16* lB = Bs + wid * 1024;
  const bf16* WArow = WA + (size_t)(q * 128 + arow) * 288 + achunk;
  const bf16* WBrow = WB + (size_t)(q * 128 + arow) * 512 + achunk;

  const int s = tid & 31;
  const int rg8 = tid >> 5;  // 0..7
  const float biA = bA[q * 128 + s], bfA = bA[q * 128 + 32 + s];
  const float bgA = bA[q * 128 + 64 + s], boA = bA[q * 128 + 96 + s];
  const float biB = bB[q * 128 + s], bfB = bB[q * 128 + 32 + s];
  const float bgB = bB[q * 128 + 64 + s], boB = bB[q * 128 + 96 + s];
  const int u = q * 32 + s;
  const size_t NH = (size_t)NB * 256;

  float c0r[16], c1r[16];
#pragma unroll
  for (int i = 0; i < 16; ++i) { c0r[i] = 0.f; c1r[i] = 0.f; }

  f32x4 acc[4][4];

#pragma unroll 1
  for (int t = 0; t < TSTEPS; ++t) {
    const int slotW = t & 1, slotR = slotW ^ 1;
    const bf16* h0r_ = h0 + (size_t)slotR * NH;
    bf16* h0w_ = h0 + (size_t)slotW * NH;
    const bf16* h1r_ = h1 + (size_t)slotR * NH;
    bf16* h1w_ = h1 + (size_t)slotW * NH;
    const int last = (t == TSTEPS - 1);

    // ================= phase A (layer 0) =================
    if (tid == 0) {
      if (t > 0) spin_ge(&cntA[rg], 8u * t);
      __threadfence();  // acquire side: invalidate stale L1/L2 before peer-h reads
    }
    __syncthreads();

#pragma unroll
    for (int i = 0; i < 4; ++i)
#pragma unroll
      for (int j = 0; j < 4; ++j) acc[i][j] = f32x4{0.f, 0.f, 0.f, 0.f};

    for (int kb = 0; kb < 9; ++kb) {
      const bf16* ga;
      int astr;
      if (kb == 8) {
        ga = feats + ((size_t)t * NB + rowbase + arow) * 32 + achunk;
        astr = 32;
      } else {
        ga = h0r_ + (size_t)(rowbase + arow) * 256 + kb * 32 + achunk;
        astr = 256;
      }
      const bf16* gb = WArow + kb * 32;
      gld_lds16(ga, lA);
      gld_lds16(ga + (size_t)16 * astr, lA + 512);
      gld_lds16(gb, lB);
      gld_lds16(gb + (size_t)16 * 288, lB + 512);
      __syncthreads();
      bf16x8 af[4], bfr[4];
#pragma unroll
      for (int i = 0; i < 4; ++i) af[i] = *(const bf16x8*)&As[(mb + i * 16 + l16) * 32 + quad * 8];
#pragma unroll
      for (int j = 0; j < 4; ++j) bfr[j] = *(const bf16x8*)&Bs[(nb + j * 16 + l16) * 32 + quad * 8];
#pragma unroll
      for (int i = 0; i < 4; ++i)
#pragma unroll
        for (int j = 0; j < 4; ++j)
          acc[i][j] = __builtin_amdgcn_mfma_f32_16x16x32_bf16(af[i], bfr[j], acc[i][j], 0, 0, 0);
      __syncthreads();
    }

    for (int half = 0; half < 2; ++half) {
      if ((wid >> 1) == half) {
#pragma unroll
        for (int i = 0; i < 4; ++i)
#pragma unroll
          for (int j = 0; j < 4; ++j)
#pragma unroll
            for (int r = 0; r < 4; ++r)
              Gs[(i * 16 + quad * 4 + r) * 132 + nb + j * 16 + l16] = acc[i][j][r];
      }
      __syncthreads();
#pragma unroll
      for (int it = 0; it < 8; ++it) {
        int rl = rg8 * 8 + it;
        int n = rowbase + half * 64 + rl;
        float gi = sigf(Gs[rl * 132 + 0 + s] + biA);
        float gf = sigf(Gs[rl * 132 + 32 + s] + bfA);
        float gg = tanhf_fast(Gs[rl * 132 + 64 + s] + bgA);
        float go = sigf(Gs[rl * 132 + 96 + s] + boA);
        float cn = gf * c0r[half * 8 + it] + gi * gg;
        float hn = go * tanhf_fast(cn);
        c0r[half * 8 + it] = cn;
        size_t ci = (size_t)n * 256 + u;
        h0w_[ci] = __float2bfloat16(hn);
        if (last) {
          out[ci] = hn;           // h layer 0
          out[2 * NH + ci] = cn;  // c layer 0
        }
      }
      __syncthreads();  // also drains stores (vmcnt(0) before s_barrier)
    }

    // publish A(t)
    if (tid == 0) {
      __threadfence();  // release: writeback L2 to coherence point
      __hip_atomic_fetch_add(&cntA[rg], 1u, __ATOMIC_RELEASE, __HIP_MEMORY_SCOPE_AGENT);
      // ================= pre-B waits =================
      spin_ge(&cntA[rg], 8u * (t + 1));
      if (t > 0) spin_ge(&cntB[rg], 8u * t);
      __threadfence();
    }
    __syncthreads();

    // ================= phase B (layer 1) =================
#pragma unroll
    for (int i = 0; i < 4; ++i)
#pragma unroll
      for (int j = 0; j < 4; ++j) acc[i][j] = f32x4{0.f, 0.f, 0.f, 0.f};

    for (int kb = 0; kb < 16; ++kb) {
      const bf16* src = (kb >= 8) ? (h1r_ + (kb - 8) * 32) : (h0w_ + kb * 32);
      const bf16* ga = src + (size_t)(rowbase + arow) * 256 + achunk;
      const bf16* gb = WBrow + kb * 32;
      gld_lds16(ga, lA);
      gld_lds16(ga + (size_t)16 * 256, lA + 512);
      gld_lds16(gb, lB);
      gld_lds16(gb + (size_t)16 * 512, lB + 512);
      __syncthreads();
      bf16x8 af[4], bfr[4];
#pragma unroll
      for (int i = 0; i < 4; ++i) af[i] = *(const bf16x8*)&As[(mb + i * 16 + l16) * 32 + quad * 8];
#pragma unroll
      for (int j = 0; j < 4; ++j) bfr[j] = *(const bf16x8*)&Bs[(nb + j * 16 + l16) * 32 + quad * 8];
#pragma unroll
      for (int i = 0; i < 4; ++i)
#pragma unroll
        for (int j = 0; j < 4; ++j)
          acc[i][j] = __builtin_amdgcn_mfma_f32_16x16x32_bf16(af[i], bfr[j], acc[i][j], 0, 0, 0);
      __syncthreads();
    }

    for (int half = 0; half < 2; ++half) {
      if ((wid >> 1) == half) {
#pragma unroll
        for (int i = 0; i < 4; ++i)
#pragma unroll
          for (int j = 0; j < 4; ++j)
#pragma unroll
            for (int r = 0; r < 4; ++r)
              Gs[(i * 16 + quad * 4 + r) * 132 + nb + j * 16 + l16] = acc[i][j][r];
      }
      __syncthreads();
#pragma unroll
      for (int it = 0; it < 8; ++it) {
        int rl = rg8 * 8 + it;
        int n = rowbase + half * 64 + rl;
        float gi = sigf(Gs[rl * 132 + 0 + s] + biB);
        float gf = sigf(Gs[rl * 132 + 32 + s] + bfB);
        float gg = tanhf_fast(Gs[rl * 132 + 64 + s] + bgB);
        float go = sigf(Gs[rl * 132 + 96 + s] + boB);
        float cn = gf * c1r[half * 8 + it] + gi * gg;
        float hn = go * tanhf_fast(cn);
        c1r[half * 8 + it] = cn;
        size_t ci = (size_t)n * 256 + u;
        h1w_[ci] = __float2bfloat16(hn);
        if (last) {
          out[NH + ci] = hn;      // h layer 1
          out[3 * NH + ci] = cn;  // c layer 1
        }
      }
      __syncthreads();
    }

    // publish B(t)
    if (tid == 0) {
      __threadfence();
      __hip_atomic_fetch_add(&cntB[rg], 1u, __ATOMIC_RELEASE, __HIP_MEMORY_SCOPE_AGENT);
    }
    // no extra barrier needed: next iteration's pre-A __syncthreads aligns waves
  }
}

extern "C" void kernel_launch(void* const* d_in, const int* in_sizes, int n_in,
                              void* d_out, int out_size, void* d_ws, size_t ws_size,
                              hipStream_t stream) {
  const float* x = (const float*)d_in[0];
  const float* coords = (const float*)d_in[1];
  const float* env = (const float*)d_in[2];
  const float* areas = (const float*)d_in[3];
  const float* bird = (const float*)d_in[4];
  const float* W_in = (const float*)d_in[5];
  const float* W_ih = (const float*)d_in[6];  // [2,1024,256]
  const float* W_hh = (const float*)d_in[7];  // [2,1024,256]
  const float* b_ih = (const float*)d_in[8];  // [2,1024]
  const float* b_hh = (const float*)d_in[9];  // [2,1024]
  float* out = (float*)d_out;

  const size_t MB = 1 << 20;
  char* w0 = (char*)d_ws;
  bf16* h0 = (bf16*)w0;                      // [2][8192][256] = 8 MB
  bf16* h1 = (bf16*)(w0 + 8 * MB);           // 8 MB
  unsigned* cntA = (unsigned*)(w0 + 16 * MB);  // 64 u32
  unsigned* cntB = cntA + 64;
  bf16* feats = (bf16*)(w0 + 17 * MB);       // 24 MB
  bf16* WA = (bf16*)(w0 + 41 * MB);          // 576 KB
  bf16* WB = (bf16*)(w0 + 42 * MB);          // 1 MB
  float* bA = (float*)(w0 + 43 * MB);
  float* bB = (float*)(w0 + 43 * MB + 4096);

  // zero h buffers (both slots) + counters
  hipMemsetAsync(w0, 0, 16 * MB + 4096, stream);

  feats_kernel<<<(NB * TSTEPS) / 256, 256, 0, stream>>>(x, coords, env, areas, bird, feats);
  packA_kernel<<<(1024 * 288) / 256, 256, 0, stream>>>(W_hh, W_ih, W_in, WA);
  packB_kernel<<<(1024 * 512) / 256, 256, 0, stream>>>(W_ih + 1024 * 256, W_hh + 1024 * 256, WB);
  packBias_kernel<<<2048 / 256, 256, 0, stream>>>(b_ih, b_hh, bA, bB);

  lstm_persistent<<<512, 256, 0, stream>>>(h0, h1, feats, WA, WB, bA, bB, cntA, cntB, out);
}

// Round 6
// 1958.815 us; speedup vs baseline: 2.5168x; 2.5168x over previous
//
#include <hip/hip_runtime.h>
#include <hip/hip_bf16.h>
#include <cstdint>

#define NB 8192
#define TSTEPS 48

typedef __hip_bfloat16 bf16;
typedef short bf16x8 __attribute__((ext_vector_type(8)));
typedef float f32x4 __attribute__((ext_vector_type(4)));

__device__ __forceinline__ float sigf(float x) { return 1.0f / (1.0f + __expf(-x)); }
__device__ __forceinline__ float tanhf_fast(float x) { return 2.0f / (1.0f + __expf(-2.0f * x)) - 1.0f; }

// CK-style async global->LDS, 16B per lane. LDS dest = wave-uniform base + lane*16.
__device__ __forceinline__ void gld_lds16(const void* g, void* l) {
  typedef const __attribute__((address_space(1))) unsigned int* gp_t;
  typedef __attribute__((address_space(3))) unsigned int* lp_t;
  __builtin_amdgcn_global_load_lds(reinterpret_cast<gp_t>(reinterpret_cast<uintptr_t>(g)),
                                   reinterpret_cast<lp_t>(reinterpret_cast<uintptr_t>(l)),
                                   16, 0, 0);
}

// ---------------- feats precompute: [T, N, 32] bf16, upper 16 cols zero ----------------
__global__ void feats_kernel(const float* __restrict__ x, const float* __restrict__ coords,
                             const float* __restrict__ env, const float* __restrict__ areas,
                             const float* __restrict__ bird, bf16* __restrict__ feats) {
  int idx = blockIdx.x * 256 + threadIdx.x;  // = t*NB + n
  int n = idx & (NB - 1);
  int t = idx >> 13;
  __align__(16) bf16 v[32];
  v[0] = __float2bfloat16(x[n * TSTEPS + t]);
  v[1] = __float2bfloat16(coords[n * 2 + 0]);
  v[2] = __float2bfloat16(coords[n * 2 + 1]);
#pragma unroll
  for (int e = 0; e < 10; ++e) v[3 + e] = __float2bfloat16(env[(n * 10 + e) * TSTEPS + t]);
  v[13] = __float2bfloat16(areas[n]);
  v[14] = __float2bfloat16(bird[(n * 2 + 0) * TSTEPS + t]);
  v[15] = __float2bfloat16(bird[(n * 2 + 1) * TSTEPS + t]);
#pragma unroll
  for (int f = 16; f < 32; ++f) v[f] = __float2bfloat16(0.0f);
  bf16* dst = feats + (size_t)idx * 32;
#pragma unroll
  for (int c = 0; c < 4; ++c) ((bf16x8*)dst)[c] = ((const bf16x8*)v)[c];
}

// ---------------- weight packing ----------------
// packed gate-column order: j' = 128*q + 32*g + s  <->  original row j = 256*g + 32*q + s
__device__ __forceinline__ int orig_row(int jp) {
  int q = jp >> 7, g = (jp >> 5) & 3, s = jp & 31;
  return g * 256 + q * 32 + s;
}

// WA: [1024, 288] = [W_hh0 (256) | Wc0 = W_ih0@W_in (16) | zeros (16)]
__global__ void packA_kernel(const float* __restrict__ W_hh0, const float* __restrict__ W_ih0,
                             const float* __restrict__ W_in, bf16* __restrict__ WA) {
  int idx = blockIdx.x * 256 + threadIdx.x;  // < 1024*288
  int jp = idx / 288, col = idx % 288;
  int j = orig_row(jp);
  float val = 0.0f;
  if (col < 256) {
    val = W_hh0[j * 256 + col];
  } else if (col < 272) {
    int f = col - 256;
    float s = 0.0f;
    for (int k = 0; k < 256; ++k) s += W_ih0[j * 256 + k] * W_in[k * 16 + f];
    val = s;
  }
  WA[(size_t)jp * 288 + col] = __float2bfloat16(val);
}

// WB: [1024, 512] = [W_ih1 (256) | W_hh1 (256)]
__global__ void packB_kernel(const float* __restrict__ W_ih1, const float* __restrict__ W_hh1,
                             bf16* __restrict__ WB) {
  int idx = blockIdx.x * 256 + threadIdx.x;  // < 1024*512
  int jp = idx >> 9, col = idx & 511;
  int j = orig_row(jp);
  float val = (col < 256) ? W_ih1[j * 256 + col] : W_hh1[j * 256 + (col - 256)];
  WB[(size_t)jp * 512 + col] = __float2bfloat16(val);
}

__global__ void packBias_kernel(const float* __restrict__ b_ih, const float* __restrict__ b_hh,
                                float* __restrict__ bA, float* __restrict__ bB) {
  int idx = blockIdx.x * 256 + threadIdx.x;  // < 2048
  int layer = idx >> 10, jp = idx & 1023;
  int j = orig_row(jp);
  float v = b_ih[layer * 1024 + j] + b_hh[layer * 1024 + j];
  if (layer == 0) bA[jp] = v; else bB[jp] = v;
}

// ---------------- fused GEMM + LSTM cell step, combined A/B phases ----------------
// phase = blockIdx.z + phase0:  0 = layer-1 at tB (B), 1 = layer-0 at tA (A).
// R6 vs R4 (LDS pipe was the bottleneck: 32 ds_read_b128 x ~16cyc per block-iter
// vs 80cyc MFMA; SQ_LDS_BANK_CONFLICT ~4cyc/read in R5's counters):
//  1. B (weights) fragments load DIRECT from global (L2-resident, 1.55MB) -> halves
//     LDS reads, moves B traffic to the TA/L2 pipe.
//  2. A staging XOR-swizzled (slot = chunk ^ (row&3), via source-lane permutation
//     since global_load_lds dest is base+lane*16) -> kills bank-conflict residue.
// Everything else (m97 2-barrier K-loop, Gs epilogue, launch structure) = R4.
__global__ __launch_bounds__(256, 4) void lstm_step(
    const bf16* __restrict__ h0r, bf16* __restrict__ h0w,
    const bf16* __restrict__ h1r, bf16* __restrict__ h1w,
    const bf16* __restrict__ feats,
    const bf16* __restrict__ WA, const bf16* __restrict__ WB,
    const float* __restrict__ bA, const float* __restrict__ bB,
    float* __restrict__ c0, float* __restrict__ c1,
    float* __restrict__ out, int tA, int tB, int phase0, int lastA, int lastB) {
  __shared__ float Gs[64 * 132];  // 33.8 KB epilogue buffer; front 8 KB aliased as As
  bf16* As = (bf16*)Gs;           // [128 rows][4 slots of 16B], swizzled

  const int tid = threadIdx.x;
  const int wid = tid >> 6, lane = tid & 63;
  const int quad = lane >> 4, l16 = lane & 15;
  const int mb = (wid >> 1) * 64, nb = (wid & 1) * 64;
  const int rowbase = blockIdx.x * 128;
  const int q = blockIdx.y;
  const int isA = blockIdx.z + phase0;  // 0 = B, 1 = A

  const bf16* Wp = isA ? WA : WB;
  const int KW = isA ? 288 : 512;
  const int KITERS = isA ? 9 : 16;
  const int t = isA ? tA : tB;

  f32x4 acc[4][4];
#pragma unroll
  for (int i = 0; i < 4; ++i)
#pragma unroll
    for (int j = 0; j < 4; ++j) acc[i][j] = f32x4{0.f, 0.f, 0.f, 0.f};

  // A staging map: wave w stages LDS rows w*32+(lane>>2) and +16; lane's LDS slot
  // is lane&3 (forced); source chunk is swizzled so slot s holds chunk s^(row&3).
  const int arow = wid * 32 + (lane >> 2);
  const int achunk = (((lane & 3) ^ ((lane >> 2) & 3)) * 8);  // swizzled source chunk
  bf16* lA = As + wid * 1024;  // wave-uniform LDS base (32 rows * 64B = 2KB = 1024 elems)

  // B direct-from-global fragment base: col = q*128 + nb + j*16 + l16, k = kb*32 + quad*8
  const bf16* wbase = Wp + (size_t)(q * 128 + nb + l16) * KW + quad * 8;

  for (int kb = 0; kb < KITERS; ++kb) {
    const bf16* Arow;
    int astr;
    if (isA && kb == 8) {
      Arow = feats + ((size_t)t * NB + rowbase) * 32;
      astr = 32;
    } else {
      const bf16* src = (!isA && kb >= 8) ? (h1r + (kb - 8) * 32) : (h0r + kb * 32);
      Arow = src + (size_t)rowbase * 256;
      astr = 256;
    }
    const bf16* ga = Arow + (size_t)arow * astr + achunk;
    gld_lds16(ga, lA);
    gld_lds16(ga + (size_t)16 * astr, lA + 512);
    bf16x8 bfr[4];
#pragma unroll
    for (int j = 0; j < 4; ++j)
      bfr[j] = *(const bf16x8*)&wbase[(size_t)(j * 16) * KW + kb * 32];
    __syncthreads();  // vmcnt drain publishes As(kb) + completes bfr regs (m97 structure)
    bf16x8 af[4];
#pragma unroll
    for (int i = 0; i < 4; ++i)
      af[i] = *(const bf16x8*)&As[(mb + i * 16 + l16) * 32 + ((quad ^ (l16 & 3)) * 8)];
#pragma unroll
    for (int i = 0; i < 4; ++i)
#pragma unroll
      for (int j = 0; j < 4; ++j)
        acc[i][j] = __builtin_amdgcn_mfma_f32_16x16x32_bf16(af[i], bfr[j], acc[i][j], 0, 0, 0);
    __syncthreads();  // retire As reads before next iteration's staging writes
  }

  // epilogue: half-block at a time through LDS (aliases As; all waves past final barrier)
  const float* bias = isA ? bA : bB;
  float* cst = isA ? c0 : c1;
  bf16* hout = isA ? h0w : h1w;
  const int last = isA ? lastA : lastB;
  float* out_h = out + (size_t)(isA ? 0 : 1) * NB * 256;
  float* out_c = out + (size_t)(isA ? 2 : 3) * NB * 256;

  const int s = tid & 31;
  const int rg = tid >> 5;  // 0..7
  const float bi = bias[q * 128 + 0 + s];
  const float bf_ = bias[q * 128 + 32 + s];
  const float bg = bias[q * 128 + 64 + s];
  const float bo = bias[q * 128 + 96 + s];
  const int u = q * 32 + s;

  for (int half = 0; half < 2; ++half) {
    if ((wid >> 1) == half) {
#pragma unroll
      for (int i = 0; i < 4; ++i)
#pragma unroll
        for (int j = 0; j < 4; ++j)
#pragma unroll
          for (int r = 0; r < 4; ++r)
            Gs[(i * 16 + quad * 4 + r) * 132 + nb + j * 16 + l16] = acc[i][j][r];
    }
    __syncthreads();
#pragma unroll
    for (int it = 0; it < 8; ++it) {
      int rl = rg * 8 + it;  // 0..63
      int n = rowbase + half * 64 + rl;
      float gi = sigf(Gs[rl * 132 + 0 + s] + bi);
      float gf = sigf(Gs[rl * 132 + 32 + s] + bf_);
      float gg = tanhf_fast(Gs[rl * 132 + 64 + s] + bg);
      float go = sigf(Gs[rl * 132 + 96 + s] + bo);
      size_t ci = (size_t)n * 256 + u;
      float c = cst[ci];
      float cn = gf * c + gi * gg;
      float hn = go * tanhf_fast(cn);
      cst[ci] = cn;
      hout[ci] = __float2bfloat16(hn);
      if (last) {
        out_h[ci] = hn;
        out_c[ci] = cn;
      }
    }
    __syncthreads();
  }
}

extern "C" void kernel_launch(void* const* d_in, const int* in_sizes, int n_in,
                              void* d_out, int out_size, void* d_ws, size_t ws_size,
                              hipStream_t stream) {
  const float* x = (const float*)d_in[0];
  const float* coords = (const float*)d_in[1];
  const float* env = (const float*)d_in[2];
  const float* areas = (const float*)d_in[3];
  const float* bird = (const float*)d_in[4];
  const float* W_in = (const float*)d_in[5];
  const float* W_ih = (const float*)d_in[6];  // [2,1024,256]
  const float* W_hh = (const float*)d_in[7];  // [2,1024,256]
  const float* b_ih = (const float*)d_in[8];  // [2,1024]
  const float* b_hh = (const float*)d_in[9];  // [2,1024]
  float* out = (float*)d_out;

  const size_t MB = 1 << 20;
  char* w0 = (char*)d_ws;
  // layout: [H0_0 4MB][H1_0 4MB][H0_1 4MB][H1_1 4MB][c0 8MB][c1 8MB][feats 24MB][WA][WB][bA][bB]
  auto H0 = [&](int i) { return (bf16*)(w0 + (size_t)i * 8 * MB); };
  auto H1 = [&](int i) { return (bf16*)(w0 + 4 * MB + (size_t)i * 8 * MB); };
  float* c0 = (float*)(w0 + 16 * MB);
  float* c1 = (float*)(w0 + 24 * MB);
  bf16* feats = (bf16*)(w0 + 32 * MB);
  bf16* WA = (bf16*)(w0 + 56 * MB);
  bf16* WB = (bf16*)(w0 + 57 * MB);
  float* bA = (float*)(w0 + 58 * MB);
  float* bB = (float*)(w0 + 58 * MB + 4096);

  // zero H0[1], H1[1] (initial state) and c0, c1 — contiguous [8MB, 32MB)
  hipMemsetAsync(w0 + 8 * MB, 0, 24 * MB, stream);

  feats_kernel<<<(NB * TSTEPS) / 256, 256, 0, stream>>>(x, coords, env, areas, bird, feats);
  packA_kernel<<<(1024 * 288) / 256, 256, 0, stream>>>(W_hh, W_ih, W_in, WA);
  packB_kernel<<<(1024 * 512) / 256, 256, 0, stream>>>(W_ih + 1024 * 256, W_hh + 1024 * 256, WB);
  packBias_kernel<<<2048 / 256, 256, 0, stream>>>(b_ih, b_hh, bA, bB);

  // A(0): reads H0[1] (zero), writes H0[0]
  lstm_step<<<dim3(64, 8, 1), 256, 0, stream>>>(
      H0(1), H0(0), H1(0), H1(1), feats, WA, WB, bA, bB, c0, c1, out,
      /*tA*/0, /*tB*/0, /*phase0*/1, /*lastA*/0, /*lastB*/0);
  // combined: z=0 -> B(s), z=1 -> A(s+1). Both read h0(s)=H0[s&1].
  for (int s2 = 0; s2 <= 46; ++s2) {
    int pa = (s2 + 1) & 1, pb = s2 & 1;
    lstm_step<<<dim3(64, 8, 2), 256, 0, stream>>>(
        H0(pb), H0(pa), H1(pa), H1(pb), feats, WA, WB, bA, bB, c0, c1, out,
        /*tA*/s2 + 1, /*tB*/s2, /*phase0*/0, /*lastA*/(s2 == 46), /*lastB*/0);
  }
  // B(47): reads H0[1], H1[0]; writes H1[1]
  lstm_step<<<dim3(64, 8, 1), 256, 0, stream>>>(
      H0(1), H0(0), H1(0), H1(1), feats, WA, WB, bA, bB, c0, c1, out,
      /*tA*/0, /*tB*/47, /*phase0*/0, /*lastA*/0, /*lastB*/1);
}

// Round 7
// 1435.227 us; speedup vs baseline: 3.4349x; 1.3648x over previous
//
#include <hip/hip_runtime.h>
#include <hip/hip_bf16.h>
#include <cstdint>

#define NB 8192
#define TSTEPS 48

typedef __hip_bfloat16 bf16;
typedef short bf16x8 __attribute__((ext_vector_type(8)));
typedef float f32x4 __attribute__((ext_vector_type(4)));

__device__ __forceinline__ float sigf(float x) { return 1.0f / (1.0f + __expf(-x)); }
__device__ __forceinline__ float tanhf_fast(float x) { return 2.0f / (1.0f + __expf(-2.0f * x)) - 1.0f; }

// CK-style async global->LDS, 16B per lane. LDS dest = wave-uniform base + lane*16.
__device__ __forceinline__ void gld_lds16(const void* g, void* l) {
  typedef const __attribute__((address_space(1))) unsigned int* gp_t;
  typedef __attribute__((address_space(3))) unsigned int* lp_t;
  __builtin_amdgcn_global_load_lds(reinterpret_cast<gp_t>(reinterpret_cast<uintptr_t>(g)),
                                   reinterpret_cast<lp_t>(reinterpret_cast<uintptr_t>(l)),
                                   16, 0, 0);
}

// ---------------- feats precompute: [T, N, 32] bf16, upper 16 cols zero ----------------
__global__ void feats_kernel(const float* __restrict__ x, const float* __restrict__ coords,
                             const float* __restrict__ env, const float* __restrict__ areas,
                             const float* __restrict__ bird, bf16* __restrict__ feats) {
  int idx = blockIdx.x * 256 + threadIdx.x;  // = t*NB + n
  int n = idx & (NB - 1);
  int t = idx >> 13;
  __align__(16) bf16 v[32];
  v[0] = __float2bfloat16(x[n * TSTEPS + t]);
  v[1] = __float2bfloat16(coords[n * 2 + 0]);
  v[2] = __float2bfloat16(coords[n * 2 + 1]);
#pragma unroll
  for (int e = 0; e < 10; ++e) v[3 + e] = __float2bfloat16(env[(n * 10 + e) * TSTEPS + t]);
  v[13] = __float2bfloat16(areas[n]);
  v[14] = __float2bfloat16(bird[(n * 2 + 0) * TSTEPS + t]);
  v[15] = __float2bfloat16(bird[(n * 2 + 1) * TSTEPS + t]);
#pragma unroll
  for (int f = 16; f < 32; ++f) v[f] = __float2bfloat16(0.0f);
  bf16* dst = feats + (size_t)idx * 32;
#pragma unroll
  for (int c = 0; c < 4; ++c) ((bf16x8*)dst)[c] = ((const bf16x8*)v)[c];
}

// ---------------- weight packing ----------------
// packed gate-column order: j' = 128*q + 32*g + s  <->  original row j = 256*g + 32*q + s
__device__ __forceinline__ int orig_row(int jp) {
  int q = jp >> 7, g = (jp >> 5) & 3, s = jp & 31;
  return g * 256 + q * 32 + s;
}

// WA: [1024, 288] = [W_hh0 (256) | Wc0 = W_ih0@W_in (16) | zeros (16)]
__global__ void packA_kernel(const float* __restrict__ W_hh0, const float* __restrict__ W_ih0,
                             const float* __restrict__ W_in, bf16* __restrict__ WA) {
  int idx = blockIdx.x * 256 + threadIdx.x;  // < 1024*288
  int jp = idx / 288, col = idx % 288;
  int j = orig_row(jp);
  float val = 0.0f;
  if (col < 256) {
    val = W_hh0[j * 256 + col];
  } else if (col < 272) {
    int f = col - 256;
    float s = 0.0f;
    for (int k = 0; k < 256; ++k) s += W_ih0[j * 256 + k] * W_in[k * 16 + f];
    val = s;
  }
  WA[(size_t)jp * 288 + col] = __float2bfloat16(val);
}

// WB: [1024, 512] = [W_ih1 (256) | W_hh1 (256)]
__global__ void packB_kernel(const float* __restrict__ W_ih1, const float* __restrict__ W_hh1,
                             bf16* __restrict__ WB) {
  int idx = blockIdx.x * 256 + threadIdx.x;  // < 1024*512
  int jp = idx >> 9, col = idx & 511;
  int j = orig_row(jp);
  float val = (col < 256) ? W_ih1[j * 256 + col] : W_hh1[j * 256 + (col - 256)];
  WB[(size_t)jp * 512 + col] = __float2bfloat16(val);
}

__global__ void packBias_kernel(const float* __restrict__ b_ih, const float* __restrict__ b_hh,
                                float* __restrict__ bA, float* __restrict__ bB) {
  int idx = blockIdx.x * 256 + threadIdx.x;  // < 2048
  int layer = idx >> 10, jp = idx & 1023;
  int j = orig_row(jp);
  float v = b_ih[layer * 1024 + j] + b_hh[layer * 1024 + j];
  if (layer == 0) bA[jp] = v; else bB[jp] = v;
}

// ---------------- fused GEMM + LSTM cell step, combined A/B phases ----------------
// phase = blockIdx.z + phase0:  0 = layer-1 at tB (B), 1 = layer-0 at tA (A).
// A: C = h0r[8192,256] @ WA cols 0..255 + feats(tA) @ WA cols 256..287 (pad to 288)
// B: C = h0r @ WB cols 0..255 + h1r @ WB cols 256..511
// K-loop/staging = R4's verified m97 2-barrier structure (R6's B-direct-from-global
// regressed: exposed per-iter global latency). R7 delta: carry state c stored as
// bf16 (compute f32 in-kernel) -> cuts 16 MB/step of the 43.5 MB HBM traffic that
// R6's counters showed moving at only ~1 TB/s (latency-bound).
__global__ __launch_bounds__(256, 4) void lstm_step(
    const bf16* __restrict__ h0r, bf16* __restrict__ h0w,
    const bf16* __restrict__ h1r, bf16* __restrict__ h1w,
    const bf16* __restrict__ feats,
    const bf16* __restrict__ WA, const bf16* __restrict__ WB,
    const float* __restrict__ bA, const float* __restrict__ bB,
    bf16* __restrict__ c0, bf16* __restrict__ c1,
    float* __restrict__ out, int tA, int tB, int phase0, int lastA, int lastB) {
  __shared__ float Gs[64 * 132];
  bf16* As = (bf16*)Gs;        // [128][32]
  bf16* Bs = As + 128 * 32;    // [128][32]

  const int tid = threadIdx.x;
  const int wid = tid >> 6, lane = tid & 63;
  const int quad = lane >> 4, l16 = lane & 15;
  const int mb = (wid >> 1) * 64, nb = (wid & 1) * 64;
  const int rowbase = blockIdx.x * 128;
  const int q = blockIdx.y;
  const int isA = blockIdx.z + phase0;  // 0 = B, 1 = A

  const bf16* Wp = isA ? WA : WB;
  const int KW = isA ? 288 : 512;
  const int KITERS = isA ? 9 : 16;
  const int t = isA ? tA : tB;

  f32x4 acc[4][4];
#pragma unroll
  for (int i = 0; i < 4; ++i)
#pragma unroll
    for (int j = 0; j < 4; ++j) acc[i][j] = f32x4{0.f, 0.f, 0.f, 0.f};

  const int arow = wid * 32 + (lane >> 2);  // staging row within 128-tile
  const int achunk = (lane & 3) * 8;        // element offset within 32-col row
  const bf16* WGrow = Wp + (size_t)(q * 128 + arow) * KW + achunk;
  bf16* lA = As + wid * 1024;  // wave-uniform LDS bases (wave stages rows wid*32..wid*32+31)
  bf16* lB = Bs + wid * 1024;

  for (int kb = 0; kb < KITERS; ++kb) {
    const bf16* Arow;
    int astr;
    if (isA && kb == 8) {
      Arow = feats + ((size_t)t * NB + rowbase) * 32;
      astr = 32;
    } else {
      const bf16* src = (!isA && kb >= 8) ? (h1r + (kb - 8) * 32) : (h0r + kb * 32);
      Arow = src + (size_t)rowbase * 256;
      astr = 256;
    }
    const bf16* ga = Arow + (size_t)arow * astr + achunk;
    const bf16* gb = WGrow + kb * 32;
    gld_lds16(ga, lA);
    gld_lds16(ga + (size_t)16 * astr, lA + 512);
    gld_lds16(gb, lB);
    gld_lds16(gb + (size_t)16 * KW, lB + 512);
    __syncthreads();  // vmcnt drain publishes staged tiles (m97-verified structure)
    bf16x8 af[4], bfr[4];
#pragma unroll
    for (int i = 0; i < 4; ++i) af[i] = *(const bf16x8*)&As[(mb + i * 16 + l16) * 32 + quad * 8];
#pragma unroll
    for (int j = 0; j < 4; ++j) bfr[j] = *(const bf16x8*)&Bs[(nb + j * 16 + l16) * 32 + quad * 8];
#pragma unroll
    for (int i = 0; i < 4; ++i)
#pragma unroll
      for (int j = 0; j < 4; ++j)
        acc[i][j] = __builtin_amdgcn_mfma_f32_16x16x32_bf16(af[i], bfr[j], acc[i][j], 0, 0, 0);
    __syncthreads();  // retire reads before next iteration's staging writes
  }

  // epilogue: half-block at a time through LDS (aliases As/Bs; all waves past final barrier)
  const float* bias = isA ? bA : bB;
  bf16* cst = isA ? c0 : c1;
  bf16* hout = isA ? h0w : h1w;
  const int last = isA ? lastA : lastB;
  float* out_h = out + (size_t)(isA ? 0 : 1) * NB * 256;
  float* out_c = out + (size_t)(isA ? 2 : 3) * NB * 256;

  const int s = tid & 31;
  const int rg = tid >> 5;  // 0..7
  const float bi = bias[q * 128 + 0 + s];
  const float bf_ = bias[q * 128 + 32 + s];
  const float bg = bias[q * 128 + 64 + s];
  const float bo = bias[q * 128 + 96 + s];
  const int u = q * 32 + s;

  for (int half = 0; half < 2; ++half) {
    if ((wid >> 1) == half) {
#pragma unroll
      for (int i = 0; i < 4; ++i)
#pragma unroll
        for (int j = 0; j < 4; ++j)
#pragma unroll
          for (int r = 0; r < 4; ++r)
            Gs[(i * 16 + quad * 4 + r) * 132 + nb + j * 16 + l16] = acc[i][j][r];
    }
    __syncthreads();
#pragma unroll
    for (int it = 0; it < 8; ++it) {
      int rl = rg * 8 + it;  // 0..63
      int n = rowbase + half * 64 + rl;
      float gi = sigf(Gs[rl * 132 + 0 + s] + bi);
      float gf = sigf(Gs[rl * 132 + 32 + s] + bf_);
      float gg = tanhf_fast(Gs[rl * 132 + 64 + s] + bg);
      float go = sigf(Gs[rl * 132 + 96 + s] + bo);
      size_t ci = (size_t)n * 256 + u;
      float c = __bfloat162float(cst[ci]);
      float cn = gf * c + gi * gg;
      float hn = go * tanhf_fast(cn);
      if (!last) cst[ci] = __float2bfloat16(cn);  // carry (bf16); dead at final step
      hout[ci] = __float2bfloat16(hn);
      if (last) {
        out_h[ci] = hn;
        out_c[ci] = cn;  // f32 output keeps full accumulator precision
      }
    }
    __syncthreads();
  }
}

extern "C" void kernel_launch(void* const* d_in, const int* in_sizes, int n_in,
                              void* d_out, int out_size, void* d_ws, size_t ws_size,
                              hipStream_t stream) {
  const float* x = (const float*)d_in[0];
  const float* coords = (const float*)d_in[1];
  const float* env = (const float*)d_in[2];
  const float* areas = (const float*)d_in[3];
  const float* bird = (const float*)d_in[4];
  const float* W_in = (const float*)d_in[5];
  const float* W_ih = (const float*)d_in[6];  // [2,1024,256]
  const float* W_hh = (const float*)d_in[7];  // [2,1024,256]
  const float* b_ih = (const float*)d_in[8];  // [2,1024]
  const float* b_hh = (const float*)d_in[9];  // [2,1024]
  float* out = (float*)d_out;

  const size_t MB = 1 << 20;
  char* w0 = (char*)d_ws;
  // layout: [H0_0 4][H1_0 4][H0_1 4][H1_1 4][c0 4][c1 4][feats 24][WA][WB][bA][bB] (MB)
  auto H0 = [&](int i) { return (bf16*)(w0 + (size_t)i * 8 * MB); };
  auto H1 = [&](int i) { return (bf16*)(w0 + 4 * MB + (size_t)i * 8 * MB); };
  bf16* c0 = (bf16*)(w0 + 16 * MB);
  bf16* c1 = (bf16*)(w0 + 20 * MB);
  bf16* feats = (bf16*)(w0 + 24 * MB);
  bf16* WA = (bf16*)(w0 + 48 * MB);
  bf16* WB = (bf16*)(w0 + 49 * MB);
  float* bA = (float*)(w0 + 50 * MB);
  float* bB = (float*)(w0 + 50 * MB + 4096);

  // zero H0[1], H1[1] (initial state) and c0, c1 — contiguous [8MB, 24MB)
  hipMemsetAsync(w0 + 8 * MB, 0, 16 * MB, stream);

  feats_kernel<<<(NB * TSTEPS) / 256, 256, 0, stream>>>(x, coords, env, areas, bird, feats);
  packA_kernel<<<(1024 * 288) / 256, 256, 0, stream>>>(W_hh, W_ih, W_in, WA);
  packB_kernel<<<(1024 * 512) / 256, 256, 0, stream>>>(W_ih + 1024 * 256, W_hh + 1024 * 256, WB);
  packBias_kernel<<<2048 / 256, 256, 0, stream>>>(b_ih, b_hh, bA, bB);

  // A(0): reads H0[1] (zero), writes H0[0]
  lstm_step<<<dim3(64, 8, 1), 256, 0, stream>>>(
      H0(1), H0(0), H1(0), H1(1), feats, WA, WB, bA, bB, c0, c1, out,
      /*tA*/0, /*tB*/0, /*phase0*/1, /*lastA*/0, /*lastB*/0);
  // combined: z=0 -> B(s), z=1 -> A(s+1). Both read h0(s)=H0[s&1].
  for (int s2 = 0; s2 <= 46; ++s2) {
    int pa = (s2 + 1) & 1, pb = s2 & 1;
    lstm_step<<<dim3(64, 8, 2), 256, 0, stream>>>(
        H0(pb), H0(pa), H1(pa), H1(pb), feats, WA, WB, bA, bB, c0, c1, out,
        /*tA*/s2 + 1, /*tB*/s2, /*phase0*/0, /*lastA*/(s2 == 46), /*lastB*/0);
  }
  // B(47): reads H0[1], H1[0]; writes H1[1]
  lstm_step<<<dim3(64, 8, 1), 256, 0, stream>>>(
      H0(1), H0(0), H1(0), H1(1), feats, WA, WB, bA, bB, c0, c1, out,
      /*tA*/0, /*tB*/47, /*phase0*/0, /*lastA*/0, /*lastB*/1);
}